// Round 1
// baseline (201.335 us; speedup 1.0000x reference)
//
#include <hip/hip_runtime.h>
#include <hip/hip_bf16.h>
#include <math.h>

#define BB 16
#define CC 512
#define NH 8
#define HD 64
#define NN 1024   // H*W
#define THREEC 1536

// Q pre-scale: (1/sqrt(64)) * log2(e)  -> softmax via raw v_exp_f32 (2^x)
#define QSCALE 0.18033688f

typedef __attribute__((ext_vector_type(8))) short bf16x8;
typedef __attribute__((ext_vector_type(4))) float f32x4;
typedef __attribute__((ext_vector_type(16))) float f32x16;

#if __has_builtin(__builtin_amdgcn_exp2f)
#define EXP2F __builtin_amdgcn_exp2f
#else
#define EXP2F exp2f
#endif

// workspace byte offsets
#define XT_OFF 0u           // bf16 x^T [b][n][c]          (16.78 MB)
#define WQ_OFF 16777216u    // bf16 w_qkv [1536][512]      (1.57 MB)
#define WP_OFF 18350080u    // bf16 w_proj [512][512]      (0.52 MB)
#define QB_OFF 18874368u    // bf16 Q (scaled QSCALE) [bh][n][d]
#define KB_OFF 35651584u    // bf16 K [bh][n][d]
#define VT_OFF 52428800u    // bf16 V^T [bh][d][n]
#define AB_OFF 69206016u    // bf16 attn-out [b][n][c]
// end 85983232 (82 MiB)

static __device__ inline unsigned short f2bf(float f) {
  union { float f; unsigned u; } v; v.f = f;
  unsigned r = v.u + 0x7fffu + ((v.u >> 16) & 1u);
  return (unsigned short)(r >> 16);
}

// pack two f32 -> two bf16 in a u32 (lo = a, hi = b)
static __device__ inline unsigned pk2bf(float a, float b) {
#if defined(__AMDGCN__) && __has_builtin(__builtin_amdgcn_cvt_pk_bf16_f32)
  typedef __attribute__((ext_vector_type(2))) __bf16 bfp2;
  union { bfp2 v; unsigned u; } z;
  z.v = __builtin_amdgcn_cvt_pk_bf16_f32(a, b);
  return z.u;
#else
  return (unsigned)f2bf(a) | ((unsigned)f2bf(b) << 16);
#endif
}

static __device__ inline void gld_lds16(const unsigned short* g, unsigned short* l) {
  __builtin_amdgcn_global_load_lds(
      (const __attribute__((address_space(1))) unsigned int*)g,
      (__attribute__((address_space(3))) unsigned int*)l, 16, 0, 0);
}

// ---------------------------------------------------------------------------
// prep_w: convert w_qkv (786432) + w_proj (262144) fp32 -> bf16
// ---------------------------------------------------------------------------
__global__ __launch_bounds__(256) void prep_w(const float* __restrict__ wqkv,
                                              const float* __restrict__ wproj,
                                              unsigned short* __restrict__ dq,
                                              unsigned short* __restrict__ dp) {
  const size_t i8 = ((size_t)blockIdx.x * 256 + threadIdx.x) * 8;
  const float* src;
  unsigned short* dst;
  if (i8 < 786432u) { src = wqkv + i8; dst = dq + i8; }
  else              { src = wproj + (i8 - 786432u); dst = dp + (i8 - 786432u); }
  float4 a = *(const float4*)src;
  float4 b = *(const float4*)(src + 4);
  unsigned short pk[8] = {f2bf(a.x), f2bf(a.y), f2bf(a.z), f2bf(a.w),
                          f2bf(b.x), f2bf(b.y), f2bf(b.z), f2bf(b.w)};
  *(uint4*)dst = *(const uint4*)pk;
}

// ---------------------------------------------------------------------------
// prep_xT: x [b][c][n] fp32 -> xT [b][n][c] bf16. 64x64 LDS tile transpose.
// ---------------------------------------------------------------------------
__global__ __launch_bounds__(256) void prep_xT(const float* __restrict__ x,
                                               unsigned short* __restrict__ xT) {
  const int b  = blockIdx.z;
  const int c0 = blockIdx.y * 64;
  const int n0 = blockIdx.x * 64;
  __shared__ float tile[64][65];
  const int t  = threadIdx.x;
  const int cl = t >> 4, n4 = (t & 15) * 4;
#pragma unroll
  for (int r = 0; r < 4; ++r) {
    float4 v = *(const float4*)&x[((size_t)b * CC + c0 + cl + 16 * r) * NN + n0 + n4];
    *(float4*)&tile[cl + 16 * r][n4] = v;
  }
  __syncthreads();
  const int nl = t >> 4, c4 = (t & 15) * 4;
#pragma unroll
  for (int r = 0; r < 4; ++r) {
    ushort4 p;
    p.x = f2bf(tile[c4 + 0][nl + 16 * r]);
    p.y = f2bf(tile[c4 + 1][nl + 16 * r]);
    p.z = f2bf(tile[c4 + 2][nl + 16 * r]);
    p.w = f2bf(tile[c4 + 3][nl + 16 * r]);
    *(ushort4*)&xT[((size_t)b * NN + n0 + nl + 16 * r) * CC + c0 + c4] = p;
  }
}

// ---------------------------------------------------------------------------
// qkv_mfma: [1536x512] @ [512x1024] per batch, bf16 MFMA, 128x128 tile BK=64.
// ---------------------------------------------------------------------------
__global__ __launch_bounds__(256) void qkv_mfma(const unsigned short* __restrict__ wq,
                                                const unsigned short* __restrict__ xT,
                                                unsigned short* __restrict__ qb,
                                                unsigned short* __restrict__ kb_,
                                                unsigned short* __restrict__ vt) {
  const int b  = blockIdx.z;
  const int o0 = blockIdx.y * 128;
  const int n0 = blockIdx.x * 128;
  const int t  = threadIdx.x;
  const int w    = t >> 6;
  const int lane = t & 63;
  const int quad = lane >> 4;
  const int l16  = lane & 15;
  const int m_off = (w >> 1) * 64;
  const int n_off = (w & 1) * 64;

  __shared__ unsigned short sm[17408];
  unsigned short* As = sm;
  unsigned short* Bs = sm + 8192;

  const int which = o0 >> 9;       // 0=Q,1=K,2=V
  const bool vmode = (which == 2);

  const int srow = lane >> 3;
  const int ssw  = ((lane & 7) ^ srow) * 8;
  const unsigned short* gA = wq + (size_t)(o0 + 32 * w + srow) * CC + ssw;
  const unsigned short* gB = xT + ((size_t)b * NN + n0 + 32 * w + srow) * CC + ssw;

  f32x4 acc[4][4] = {};

  for (int c0 = 0; c0 < CC; c0 += 64) {
    __syncthreads();
#pragma unroll
    for (int L = 0; L < 4; ++L) {
      gld_lds16(gA + (size_t)(8 * L) * CC + c0, &As[(32 * w + 8 * L) * 64]);
      gld_lds16(gB + (size_t)(8 * L) * CC + c0, &Bs[(32 * w + 8 * L) * 64]);
    }
    __syncthreads();
    const unsigned short* Af = vmode ? Bs : As;
    const unsigned short* Bf = vmode ? As : Bs;
#pragma unroll
    for (int ks = 0; ks < 2; ++ks) {
      const int ph = ((ks * 4 + quad) ^ (l16 & 7)) * 8;
      bf16x8 af[4], bfr[4];
#pragma unroll
      for (int i = 0; i < 4; ++i) {
        af[i]  = *(const bf16x8*)&Af[(m_off + 16 * i + l16) * 64 + ph];
        bfr[i] = *(const bf16x8*)&Bf[(n_off + 16 * i + l16) * 64 + ph];
      }
#pragma unroll
      for (int i = 0; i < 4; ++i)
#pragma unroll
        for (int j = 0; j < 4; ++j)
          acc[i][j] = __builtin_amdgcn_mfma_f32_16x16x32_bf16(af[i], bfr[j], acc[i][j], 0, 0, 0);
    }
  }

  __syncthreads();
  const float sc = (which == 0) ? QSCALE : 1.0f;
#pragma unroll
  for (int i = 0; i < 4; ++i) {
#pragma unroll
    for (int j = 0; j < 4; ++j) {
      const int Drow = m_off + 16 * i + quad * 4;
      const int Dcol = n_off + 16 * j + l16;
      ushort4 p;
      p.x = f2bf(acc[i][j][0] * sc);
      p.y = f2bf(acc[i][j][1] * sc);
      p.z = f2bf(acc[i][j][2] * sc);
      p.w = f2bf(acc[i][j][3] * sc);
      *(ushort4*)&sm[Dcol * 136 + Drow] = p;
    }
  }
  __syncthreads();
  const int lrow = t >> 1;
  const int half = t & 1;
  const unsigned short* src = &sm[lrow * 136 + 64 * half];
  if (!vmode) {
    const int hh = ((o0 >> 6) & 7) + half;
    unsigned short* dst = (which == 0 ? qb : kb_) +
        ((size_t)(b * NH + hh) * NN + n0 + lrow) * HD;
#pragma unroll
    for (int i = 0; i < 8; ++i) *(uint4*)(dst + 8 * i) = *(const uint4*)(src + 8 * i);
  } else {
    const int hh = ((o0 + lrow) >> 6) & 7;
    const int d  = lrow & 63;
    unsigned short* dst = vt + ((size_t)(b * NH + hh) * HD + d) * NN + n0 + 64 * half;
#pragma unroll
    for (int i = 0; i < 8; ++i) *(uint4*)(dst + 8 * i) = *(const uint4*)(src + 8 * i);
  }
}

// ---------------------------------------------------------------------------
// attn_mfma v4: 32x32x16 MFMA, no-max softmax (exp2, Q pre-scaled by log2e/8).
// Key-permuted A-operand reads (rho = swap bits 2,3 of lane) make packed
// S^T C-regs directly usable as the PV B-fragment -> zero cross-lane swaps.
// v4 change: DOUBLE-BUFFERED K/V staging with stage-after-barrier ordering.
// The loads for chunk i+1 are issued immediately after the barrier that
// publishes chunk i; the NEXT barrier's implicit vmcnt(0) is the wait, so
// each chunk's global_load_lds has an entire compute phase in flight
// (T3-minimum pipeline, one barrier per chunk instead of two).
// s_setprio(1) wraps the MFMA clusters (T5; phase-split now exists).
// ---------------------------------------------------------------------------
__global__ __launch_bounds__(256) void attn_mfma(const unsigned short* __restrict__ Qg,
                                                 const unsigned short* __restrict__ Kg,
                                                 const unsigned short* __restrict__ Vtg,
                                                 unsigned short* __restrict__ attnB) {
  const int bh = blockIdx.x;     // id % 8 == bh % 8 -> XCD affinity
  const int b  = bh >> 3;
  const int h  = bh & 7;
  const int n0 = blockIdx.y * 128;
  const int t  = threadIdx.x;
  const int w    = t >> 6;
  const int lane = t & 63;
  const int l31  = lane & 31;
  const int hi   = lane >> 5;

  // 32 KiB: two staging buffers, each {K 4096 shorts | V 4096 shorts},
  // XOR-swizzled rows of 64 shorts. Epilogue reuses first 9216 shorts.
  __shared__ unsigned short sm[16384];

  // Q B-fragments (whole kernel): B[n=query=l31][k=d=16c+8hi+j]
  const unsigned short* qrow = Qg + ((size_t)bh * NN + n0 + w * 32 + l31) * HD + hi * 8;
  bf16x8 qf[4];
#pragma unroll
  for (int c = 0; c < 4; ++c) qf[c] = *(const bf16x8*)(qrow + 16 * c);

  // K A-row permutation: rho(l) swaps bits 2 and 3
  const int krow = (l31 & ~12) | ((l31 & 4) << 1) | ((l31 & 8) >> 1);
  const int ksw  = krow & 7;
  const int vsw  = l31 & 7;

  f32x16 oacc[2] = {};   // O^T: D[m=d][n=query]
  float lx = 0.f, ly = 0.f;

  // staging: wave w covers rows [16w,16w+16) of both K (keys) and V^T (d).
  const int srow = lane >> 3;                     // 0..7
  const int sgrp = (lane & 7) ^ (srow & 7);       // swizzled source col group
  const unsigned short* kstage = Kg + (size_t)bh * NN * HD +
                                 (size_t)(16 * w + srow) * HD + sgrp * 8;
  const unsigned short* vstage = Vtg + (size_t)bh * HD * NN +
                                 (size_t)(16 * w + srow) * NN + sgrp * 8;
  const int kso0 = (16 * w) * 64;
  const int kso1 = (16 * w + 8) * 64;

  auto stage = [&](int j0, int p) {
    unsigned short* Kp = sm + p * 8192;
    unsigned short* Vp = Kp + 4096;
    gld_lds16(kstage + (size_t)j0 * HD, Kp + kso0);
    gld_lds16(kstage + (size_t)(j0 + 8) * HD, Kp + kso1);
    gld_lds16(vstage + j0, Vp + kso0);
    gld_lds16(vstage + (size_t)8 * NN + j0, Vp + kso1);
  };

  // prologue: chunk 0 into buffer 0 (no overlap available for the first one)
  stage(0, 0);
  int cur = 0;

#pragma unroll 1
  for (int j0 = 0; j0 < NN; j0 += 64) {
    // implicit s_waitcnt vmcnt(0) here drains chunk-j0 loads (in flight for
    // a full compute phase), then publishes them to all waves.
    __syncthreads();
    if (j0 + 64 < NN) stage(j0 + 64, cur ^ 1);   // overwrite chunk j0-64's buf

    const unsigned short* Ks = sm + cur * 8192;  // [key][d] rows of 64, swz
    const unsigned short* Vt = Ks + 4096;        // [d][key] rows of 64, swz

#pragma unroll
    for (int kb = 0; kb < 2; ++kb) {
      // S^T: A[m]=K row rho(m) (32 keys), B=Q; contract over d
      f32x16 st = {};
      const unsigned short* krp = &Ks[(32 * kb + krow) * 64];
      __builtin_amdgcn_s_setprio(1);
#pragma unroll
      for (int c = 0; c < 4; ++c) {
        bf16x8 kf = *(const bf16x8*)(krp + (((2 * c + hi) ^ ksw) * 8));
        st = __builtin_amdgcn_mfma_f32_32x32x16_bf16(kf, qf[c], st, 0, 0, 0);
      }
      __builtin_amdgcn_s_setprio(0);
      // exp2 (Q carries log2e/8) + l accumulation
      float e[16];
#pragma unroll
      for (int i = 0; i < 8; ++i) {
        e[2 * i]     = EXP2F(st[2 * i]);
        e[2 * i + 1] = EXP2F(st[2 * i + 1]);
        lx += e[2 * i];
        ly += e[2 * i + 1];
      }
      // packed P pairs ARE the PV B-fragment (key permutation absorbed rho)
      unsigned P[8];
#pragma unroll
      for (int i = 0; i < 8; ++i) P[i] = pk2bf(e[2 * i], e[2 * i + 1]);

      __builtin_amdgcn_s_setprio(1);
#pragma unroll
      for (int g = 0; g < 2; ++g) {
        union { unsigned u[4]; bf16x8 v; } cv;
        cv.u[0] = P[4 * g + 0]; cv.u[1] = P[4 * g + 1];
        cv.u[2] = P[4 * g + 2]; cv.u[3] = P[4 * g + 3];
#pragma unroll
        for (int mt = 0; mt < 2; ++mt) {
          const int vrow = 32 * mt + l31;
          bf16x8 vf = *(const bf16x8*)&Vt[vrow * 64 + (((4 * kb + 2 * g + hi) ^ vsw) * 8)];
          oacc[mt] = __builtin_amdgcn_mfma_f32_32x32x16_bf16(vf, cv.v, oacc[mt], 0, 0, 0);
        }
      }
      __builtin_amdgcn_s_setprio(0);
    }
    cur ^= 1;
  }

  float lsum = lx + ly;
  lsum += __shfl_xor(lsum, 32);
  const float inv = 1.0f / lsum;

  // epilogue: wave-private LDS [query][d] (pitch 72), then 64B global writes
  __syncthreads();
  unsigned short* Es = sm + w * 2304;   // 32 * 72 shorts per wave
#pragma unroll
  for (int mt = 0; mt < 2; ++mt) {
#pragma unroll
    for (int rr = 0; rr < 4; ++rr) {
      const int d = 32 * mt + 8 * rr + 4 * hi;
      ushort4 p;
      p.x = f2bf(oacc[mt][4 * rr + 0] * inv);
      p.y = f2bf(oacc[mt][4 * rr + 1] * inv);
      p.z = f2bf(oacc[mt][4 * rr + 2] * inv);
      p.w = f2bf(oacc[mt][4 * rr + 3] * inv);
      *(ushort4*)&Es[l31 * 72 + d] = p;
    }
  }
  const int q    = lane >> 1;
  const int half = lane & 1;
  const unsigned short* src = &Es[q * 72 + 32 * half];
  unsigned short* gdst = attnB + ((size_t)b * NN + n0 + w * 32 + q) * CC + h * HD + 32 * half;
#pragma unroll
  for (int i = 0; i < 4; ++i) *(uint4*)(gdst + 8 * i) = *(const uint4*)(src + 8 * i);
}

// ---------------------------------------------------------------------------
// proj_mfma: out = w_proj @ attn + bias, bf16 MFMA, fp32 out [b][c][n].
// ---------------------------------------------------------------------------
__global__ __launch_bounds__(256) void proj_mfma(const unsigned short* __restrict__ wp,
                                                 const unsigned short* __restrict__ aB,
                                                 const float* __restrict__ bias,
                                                 float* __restrict__ out) {
  const int b  = blockIdx.z;
  const int o0 = blockIdx.y * 128;
  const int n0 = blockIdx.x * 128;
  const int t  = threadIdx.x;
  const int w    = t >> 6;
  const int lane = t & 63;
  const int quad = lane >> 4;
  const int l16  = lane & 15;
  const int m_off = (w >> 1) * 64;
  const int n_off = (w & 1) * 64;

  __shared__ unsigned short sm[16384];
  unsigned short* As = sm;
  unsigned short* Bs = sm + 8192;

  const int srow = lane >> 3;
  const int ssw  = ((lane & 7) ^ srow) * 8;
  const unsigned short* gA = wp + (size_t)(o0 + 32 * w + srow) * CC + ssw;
  const unsigned short* gB = aB + ((size_t)b * NN + n0 + 32 * w + srow) * CC + ssw;

  f32x4 acc[4][4] = {};

  for (int c0 = 0; c0 < CC; c0 += 64) {
    __syncthreads();
#pragma unroll
    for (int L = 0; L < 4; ++L) {
      gld_lds16(gA + (size_t)(8 * L) * CC + c0, &As[(32 * w + 8 * L) * 64]);
      gld_lds16(gB + (size_t)(8 * L) * CC + c0, &Bs[(32 * w + 8 * L) * 64]);
    }
    __syncthreads();
#pragma unroll
    for (int ks = 0; ks < 2; ++ks) {
      const int ph = ((ks * 4 + quad) ^ (l16 & 7)) * 8;
      bf16x8 af[4], bfr[4];
#pragma unroll
      for (int i = 0; i < 4; ++i) {
        af[i]  = *(const bf16x8*)&As[(m_off + 16 * i + l16) * 64 + ph];
        bfr[i] = *(const bf16x8*)&Bs[(n_off + 16 * i + l16) * 64 + ph];
      }
#pragma unroll
      for (int i = 0; i < 4; ++i)
#pragma unroll
        for (int j = 0; j < 4; ++j)
          acc[i][j] = __builtin_amdgcn_mfma_f32_16x16x32_bf16(af[i], bfr[j], acc[i][j], 0, 0, 0);
    }
  }

#pragma unroll
  for (int i = 0; i < 4; ++i) {
#pragma unroll
    for (int r = 0; r < 4; ++r) {
      const int o = o0 + m_off + 16 * i + quad * 4 + r;
      const float bv = bias[o];
      float* orow = out + ((size_t)b * CC + o) * NN + n0 + n_off;
#pragma unroll
      for (int j = 0; j < 4; ++j)
        orow[16 * j + l16] = acc[i][j][r] + bv;
    }
  }
}

// ---------------------------------------------------------------------------
extern "C" void kernel_launch(void* const* d_in, const int* in_sizes, int n_in,
                              void* d_out, int out_size, void* d_ws, size_t ws_size,
                              hipStream_t stream) {
  const float* x      = (const float*)d_in[0];
  const float* w_qkv  = (const float*)d_in[1];
  const float* w_proj = (const float*)d_in[2];
  const float* b_proj = (const float*)d_in[3];
  char* wsb  = (char*)d_ws;
  float* out = (float*)d_out;

  unsigned short* xT  = (unsigned short*)(wsb + XT_OFF);
  unsigned short* wq  = (unsigned short*)(wsb + WQ_OFF);
  unsigned short* wp  = (unsigned short*)(wsb + WP_OFF);
  unsigned short* qb  = (unsigned short*)(wsb + QB_OFF);
  unsigned short* kb_ = (unsigned short*)(wsb + KB_OFF);
  unsigned short* vt  = (unsigned short*)(wsb + VT_OFF);
  unsigned short* aB  = (unsigned short*)(wsb + AB_OFF);

  prep_w<<<512, 256, 0, stream>>>(w_qkv, w_proj, wq, wp);
  prep_xT<<<dim3(16, 8, BB), 256, 0, stream>>>(x, xT);
  qkv_mfma<<<dim3(8, 12, BB), 256, 0, stream>>>(wq, xT, qb, kb_, vt);
  attn_mfma<<<dim3(BB * NH, NN / 128), 256, 0, stream>>>(qb, kb_, vt, aB);
  proj_mfma<<<dim3(8, 4, BB), 256, 0, stream>>>(wp, aB, b_proj, out);
}

// Round 2
// 194.616 us; speedup vs baseline: 1.0345x; 1.0345x over previous
//
#include <hip/hip_runtime.h>
#include <hip/hip_bf16.h>
#include <math.h>

#define BB 16
#define CC 512
#define NH 8
#define HD 64
#define NN 1024   // H*W
#define THREEC 1536

// Q pre-scale: (1/sqrt(64)) * log2(e)  -> softmax via raw v_exp_f32 (2^x)
#define QSCALE 0.18033688f

typedef __attribute__((ext_vector_type(8))) short bf16x8;
typedef __attribute__((ext_vector_type(4))) float f32x4;
typedef __attribute__((ext_vector_type(16))) float f32x16;

#if __has_builtin(__builtin_amdgcn_exp2f)
#define EXP2F __builtin_amdgcn_exp2f
#else
#define EXP2F exp2f
#endif

// workspace byte offsets
#define XT_OFF 0u           // bf16 x^T [b][n][c]          (16.78 MB)
#define WQ_OFF 16777216u    // bf16 w_qkv [1536][512]      (1.57 MB)
#define WP_OFF 18350080u    // bf16 w_proj [512][512]      (0.52 MB)
#define QB_OFF 18874368u    // bf16 Q (scaled QSCALE) [bh][n][d]
#define KB_OFF 35651584u    // bf16 K [bh][n][d]
#define VT_OFF 52428800u    // bf16 V^T [bh][d][n]
#define AB_OFF 69206016u    // bf16 attn-out [b][n][c]
// end 85983232 (82 MiB)

static __device__ inline unsigned short f2bf(float f) {
  union { float f; unsigned u; } v; v.f = f;
  unsigned r = v.u + 0x7fffu + ((v.u >> 16) & 1u);
  return (unsigned short)(r >> 16);
}

// pack two f32 -> two bf16 in a u32 (lo = a, hi = b)
static __device__ inline unsigned pk2bf(float a, float b) {
#if defined(__AMDGCN__) && __has_builtin(__builtin_amdgcn_cvt_pk_bf16_f32)
  typedef __attribute__((ext_vector_type(2))) __bf16 bfp2;
  union { bfp2 v; unsigned u; } z;
  z.v = __builtin_amdgcn_cvt_pk_bf16_f32(a, b);
  return z.u;
#else
  return (unsigned)f2bf(a) | ((unsigned)f2bf(b) << 16);
#endif
}

static __device__ inline void gld_lds16(const unsigned short* g, unsigned short* l) {
  __builtin_amdgcn_global_load_lds(
      (const __attribute__((address_space(1))) unsigned int*)g,
      (__attribute__((address_space(3))) unsigned int*)l, 16, 0, 0);
}

// ---------------------------------------------------------------------------
// prep_w: convert w_qkv (786432) + w_proj (262144) fp32 -> bf16
// ---------------------------------------------------------------------------
__global__ __launch_bounds__(256) void prep_w(const float* __restrict__ wqkv,
                                              const float* __restrict__ wproj,
                                              unsigned short* __restrict__ dq,
                                              unsigned short* __restrict__ dp) {
  const size_t i8 = ((size_t)blockIdx.x * 256 + threadIdx.x) * 8;
  const float* src;
  unsigned short* dst;
  if (i8 < 786432u) { src = wqkv + i8; dst = dq + i8; }
  else              { src = wproj + (i8 - 786432u); dst = dp + (i8 - 786432u); }
  float4 a = *(const float4*)src;
  float4 b = *(const float4*)(src + 4);
  unsigned short pk[8] = {f2bf(a.x), f2bf(a.y), f2bf(a.z), f2bf(a.w),
                          f2bf(b.x), f2bf(b.y), f2bf(b.z), f2bf(b.w)};
  *(uint4*)dst = *(const uint4*)pk;
}

// ---------------------------------------------------------------------------
// prep_xT: x [b][c][n] fp32 -> xT [b][n][c] bf16. 64x64 LDS tile transpose.
// ---------------------------------------------------------------------------
__global__ __launch_bounds__(256) void prep_xT(const float* __restrict__ x,
                                               unsigned short* __restrict__ xT) {
  const int b  = blockIdx.z;
  const int c0 = blockIdx.y * 64;
  const int n0 = blockIdx.x * 64;
  __shared__ float tile[64][65];
  const int t  = threadIdx.x;
  const int cl = t >> 4, n4 = (t & 15) * 4;
#pragma unroll
  for (int r = 0; r < 4; ++r) {
    float4 v = *(const float4*)&x[((size_t)b * CC + c0 + cl + 16 * r) * NN + n0 + n4];
    *(float4*)&tile[cl + 16 * r][n4] = v;
  }
  __syncthreads();
  const int nl = t >> 4, c4 = (t & 15) * 4;
#pragma unroll
  for (int r = 0; r < 4; ++r) {
    ushort4 p;
    p.x = f2bf(tile[c4 + 0][nl + 16 * r]);
    p.y = f2bf(tile[c4 + 1][nl + 16 * r]);
    p.z = f2bf(tile[c4 + 2][nl + 16 * r]);
    p.w = f2bf(tile[c4 + 3][nl + 16 * r]);
    *(ushort4*)&xT[((size_t)b * NN + n0 + nl + 16 * r) * CC + c0 + c4] = p;
  }
}

// ---------------------------------------------------------------------------
// qkv_mfma: [1536x512] @ [512x1024] per batch, bf16 MFMA, 128x128 tile BK=64.
// ---------------------------------------------------------------------------
__global__ __launch_bounds__(256) void qkv_mfma(const unsigned short* __restrict__ wq,
                                                const unsigned short* __restrict__ xT,
                                                unsigned short* __restrict__ qb,
                                                unsigned short* __restrict__ kb_,
                                                unsigned short* __restrict__ vt) {
  const int b  = blockIdx.z;
  const int o0 = blockIdx.y * 128;
  const int n0 = blockIdx.x * 128;
  const int t  = threadIdx.x;
  const int w    = t >> 6;
  const int lane = t & 63;
  const int quad = lane >> 4;
  const int l16  = lane & 15;
  const int m_off = (w >> 1) * 64;
  const int n_off = (w & 1) * 64;

  __shared__ unsigned short sm[17408];
  unsigned short* As = sm;
  unsigned short* Bs = sm + 8192;

  const int which = o0 >> 9;       // 0=Q,1=K,2=V
  const bool vmode = (which == 2);

  const int srow = lane >> 3;
  const int ssw  = ((lane & 7) ^ srow) * 8;
  const unsigned short* gA = wq + (size_t)(o0 + 32 * w + srow) * CC + ssw;
  const unsigned short* gB = xT + ((size_t)b * NN + n0 + 32 * w + srow) * CC + ssw;

  f32x4 acc[4][4] = {};

  for (int c0 = 0; c0 < CC; c0 += 64) {
    __syncthreads();
#pragma unroll
    for (int L = 0; L < 4; ++L) {
      gld_lds16(gA + (size_t)(8 * L) * CC + c0, &As[(32 * w + 8 * L) * 64]);
      gld_lds16(gB + (size_t)(8 * L) * CC + c0, &Bs[(32 * w + 8 * L) * 64]);
    }
    __syncthreads();
    const unsigned short* Af = vmode ? Bs : As;
    const unsigned short* Bf = vmode ? As : Bs;
#pragma unroll
    for (int ks = 0; ks < 2; ++ks) {
      const int ph = ((ks * 4 + quad) ^ (l16 & 7)) * 8;
      bf16x8 af[4], bfr[4];
#pragma unroll
      for (int i = 0; i < 4; ++i) {
        af[i]  = *(const bf16x8*)&Af[(m_off + 16 * i + l16) * 64 + ph];
        bfr[i] = *(const bf16x8*)&Bf[(n_off + 16 * i + l16) * 64 + ph];
      }
#pragma unroll
      for (int i = 0; i < 4; ++i)
#pragma unroll
        for (int j = 0; j < 4; ++j)
          acc[i][j] = __builtin_amdgcn_mfma_f32_16x16x32_bf16(af[i], bfr[j], acc[i][j], 0, 0, 0);
    }
  }

  __syncthreads();
  const float sc = (which == 0) ? QSCALE : 1.0f;
#pragma unroll
  for (int i = 0; i < 4; ++i) {
#pragma unroll
    for (int j = 0; j < 4; ++j) {
      const int Drow = m_off + 16 * i + quad * 4;
      const int Dcol = n_off + 16 * j + l16;
      ushort4 p;
      p.x = f2bf(acc[i][j][0] * sc);
      p.y = f2bf(acc[i][j][1] * sc);
      p.z = f2bf(acc[i][j][2] * sc);
      p.w = f2bf(acc[i][j][3] * sc);
      *(ushort4*)&sm[Dcol * 136 + Drow] = p;
    }
  }
  __syncthreads();
  const int lrow = t >> 1;
  const int half = t & 1;
  const unsigned short* src = &sm[lrow * 136 + 64 * half];
  if (!vmode) {
    const int hh = ((o0 >> 6) & 7) + half;
    unsigned short* dst = (which == 0 ? qb : kb_) +
        ((size_t)(b * NH + hh) * NN + n0 + lrow) * HD;
#pragma unroll
    for (int i = 0; i < 8; ++i) *(uint4*)(dst + 8 * i) = *(const uint4*)(src + 8 * i);
  } else {
    const int hh = ((o0 + lrow) >> 6) & 7;
    const int d  = lrow & 63;
    unsigned short* dst = vt + ((size_t)(b * NH + hh) * HD + d) * NN + n0 + 64 * half;
#pragma unroll
    for (int i = 0; i < 8; ++i) *(uint4*)(dst + 8 * i) = *(const uint4*)(src + 8 * i);
  }
}

// ---------------------------------------------------------------------------
// attn_mfma v5: 32x32x16 MFMA, no-max softmax (exp2, Q pre-scaled by log2e/8).
// Key-permuted A-operand reads (rho = swap bits 2,3 of lane) make packed
// S^T C-regs directly usable as the PV B-fragment -> zero cross-lane swaps.
// v5 change: softmax denominator moved OFF the VALU onto the MFMA pipe:
// l[q] = sum_k P[k][q] computed as lacc = mfma(ones, P_frag, lacc)
// (4 extra MFMA/chunk on a 23%-utilized pipe, deleting 32 v_add_f32/chunk
// on the 53%-busy VALU and the final shfl_xor; l is summed from the same
// bf16-quantized P that PV uses, so O/l quantization partially cancels).
// Also: hoisted zero C-vector for QK init (kills per-kb v_movs), e[] array
// eliminated (direct pk2bf(exp2,exp2)). Double-buffered staging retained.
// ---------------------------------------------------------------------------
__global__ __launch_bounds__(256) void attn_mfma(const unsigned short* __restrict__ Qg,
                                                 const unsigned short* __restrict__ Kg,
                                                 const unsigned short* __restrict__ Vtg,
                                                 unsigned short* __restrict__ attnB) {
  const int bh = blockIdx.x;     // id % 8 == bh % 8 -> XCD affinity
  const int b  = bh >> 3;
  const int h  = bh & 7;
  const int n0 = blockIdx.y * 128;
  const int t  = threadIdx.x;
  const int w    = t >> 6;
  const int lane = t & 63;
  const int l31  = lane & 31;
  const int hi   = lane >> 5;

  // 32 KiB: two staging buffers, each {K 4096 shorts | V 4096 shorts},
  // XOR-swizzled rows of 64 shorts. Epilogue reuses first 9216 shorts.
  __shared__ unsigned short sm[16384];

  // Q B-fragments (whole kernel): B[n=query=l31][k=d=16c+8hi+j]
  const unsigned short* qrow = Qg + ((size_t)bh * NN + n0 + w * 32 + l31) * HD + hi * 8;
  bf16x8 qf[4];
#pragma unroll
  for (int c = 0; c < 4; ++c) qf[c] = *(const bf16x8*)(qrow + 16 * c);

  // K A-row permutation: rho(l) swaps bits 2 and 3
  const int krow = (l31 & ~12) | ((l31 & 4) << 1) | ((l31 & 8) >> 1);
  const int ksw  = krow & 7;
  const int vsw  = l31 & 7;

  // hoisted constants: zero C-input, bf16 ones A-fragment for l-reduction
  const f32x16 fz = {};
  const short ONE = 0x3F80;                // bf16 1.0
  const bf16x8 onesv = {ONE, ONE, ONE, ONE, ONE, ONE, ONE, ONE};

  f32x16 oacc[2] = {};   // O^T: D[m=d][n=query]
  f32x16 lacc = {};      // every row m = l[q] (ones @ P)

  // staging: wave w covers rows [16w,16w+16) of both K (keys) and V^T (d).
  const int srow = lane >> 3;                     // 0..7
  const int sgrp = (lane & 7) ^ (srow & 7);       // swizzled source col group
  const unsigned short* kstage = Kg + (size_t)bh * NN * HD +
                                 (size_t)(16 * w + srow) * HD + sgrp * 8;
  const unsigned short* vstage = Vtg + (size_t)bh * HD * NN +
                                 (size_t)(16 * w + srow) * NN + sgrp * 8;
  const int kso0 = (16 * w) * 64;
  const int kso1 = (16 * w + 8) * 64;

  auto stage = [&](int j0, int p) {
    unsigned short* Kp = sm + p * 8192;
    unsigned short* Vp = Kp + 4096;
    gld_lds16(kstage + (size_t)j0 * HD, Kp + kso0);
    gld_lds16(kstage + (size_t)(j0 + 8) * HD, Kp + kso1);
    gld_lds16(vstage + j0, Vp + kso0);
    gld_lds16(vstage + (size_t)8 * NN + j0, Vp + kso1);
  };

  // prologue: chunk 0 into buffer 0
  stage(0, 0);
  int cur = 0;

#pragma unroll 1
  for (int j0 = 0; j0 < NN; j0 += 64) {
    // implicit s_waitcnt vmcnt(0) here drains chunk-j0 loads (in flight for
    // a full compute phase), then publishes them to all waves.
    __syncthreads();
    if (j0 + 64 < NN) stage(j0 + 64, cur ^ 1);   // overwrite chunk j0-64's buf

    const unsigned short* Ks = sm + cur * 8192;  // [key][d] rows of 64, swz
    const unsigned short* Vt = Ks + 4096;        // [d][key] rows of 64, swz

#pragma unroll
    for (int kb = 0; kb < 2; ++kb) {
      // S^T: A[m]=K row rho(m) (32 keys), B=Q; contract over d
      const unsigned short* krp = &Ks[(32 * kb + krow) * 64];
      __builtin_amdgcn_s_setprio(1);
      bf16x8 kf0 = *(const bf16x8*)(krp + (((0 + hi) ^ ksw) * 8));
      f32x16 st = __builtin_amdgcn_mfma_f32_32x32x16_bf16(kf0, qf[0], fz, 0, 0, 0);
#pragma unroll
      for (int c = 1; c < 4; ++c) {
        bf16x8 kf = *(const bf16x8*)(krp + (((2 * c + hi) ^ ksw) * 8));
        st = __builtin_amdgcn_mfma_f32_32x32x16_bf16(kf, qf[c], st, 0, 0, 0);
      }
      __builtin_amdgcn_s_setprio(0);
      // exp2 (Q carries log2e/8), packed directly: P pairs ARE the PV
      // B-fragment (key permutation absorbed rho)
      unsigned P[8];
#pragma unroll
      for (int i = 0; i < 8; ++i)
        P[i] = pk2bf(EXP2F(st[2 * i]), EXP2F(st[2 * i + 1]));

      __builtin_amdgcn_s_setprio(1);
#pragma unroll
      for (int g = 0; g < 2; ++g) {
        union { unsigned u[4]; bf16x8 v; } cv;
        cv.u[0] = P[4 * g + 0]; cv.u[1] = P[4 * g + 1];
        cv.u[2] = P[4 * g + 2]; cv.u[3] = P[4 * g + 3];
        // l-reduction on the MFMA pipe: lacc rows += sum_k P[k][q]
        lacc = __builtin_amdgcn_mfma_f32_32x32x16_bf16(onesv, cv.v, lacc, 0, 0, 0);
#pragma unroll
        for (int mt = 0; mt < 2; ++mt) {
          const int vrow = 32 * mt + l31;
          bf16x8 vf = *(const bf16x8*)&Vt[vrow * 64 + (((4 * kb + 2 * g + hi) ^ vsw) * 8)];
          oacc[mt] = __builtin_amdgcn_mfma_f32_32x32x16_bf16(vf, cv.v, oacc[mt], 0, 0, 0);
        }
      }
      __builtin_amdgcn_s_setprio(0);
    }
    cur ^= 1;
  }

  // every lane's column q=l31 holds the full l[q] in every lacc row
  const float inv = 1.0f / lacc[0];

  // epilogue: wave-private LDS [query][d] (pitch 72), then 64B global writes
  __syncthreads();
  unsigned short* Es = sm + w * 2304;   // 32 * 72 shorts per wave
#pragma unroll
  for (int mt = 0; mt < 2; ++mt) {
#pragma unroll
    for (int rr = 0; rr < 4; ++rr) {
      const int d = 32 * mt + 8 * rr + 4 * hi;
      ushort4 p;
      p.x = f2bf(oacc[mt][4 * rr + 0] * inv);
      p.y = f2bf(oacc[mt][4 * rr + 1] * inv);
      p.z = f2bf(oacc[mt][4 * rr + 2] * inv);
      p.w = f2bf(oacc[mt][4 * rr + 3] * inv);
      *(ushort4*)&Es[l31 * 72 + d] = p;
    }
  }
  const int q    = lane >> 1;
  const int half = lane & 1;
  const unsigned short* src = &Es[q * 72 + 32 * half];
  unsigned short* gdst = attnB + ((size_t)b * NN + n0 + w * 32 + q) * CC + h * HD + 32 * half;
#pragma unroll
  for (int i = 0; i < 4; ++i) *(uint4*)(gdst + 8 * i) = *(const uint4*)(src + 8 * i);
}

// ---------------------------------------------------------------------------
// proj_mfma: out = w_proj @ attn + bias, bf16 MFMA, fp32 out [b][c][n].
// ---------------------------------------------------------------------------
__global__ __launch_bounds__(256) void proj_mfma(const unsigned short* __restrict__ wp,
                                                 const unsigned short* __restrict__ aB,
                                                 const float* __restrict__ bias,
                                                 float* __restrict__ out) {
  const int b  = blockIdx.z;
  const int o0 = blockIdx.y * 128;
  const int n0 = blockIdx.x * 128;
  const int t  = threadIdx.x;
  const int w    = t >> 6;
  const int lane = t & 63;
  const int quad = lane >> 4;
  const int l16  = lane & 15;
  const int m_off = (w >> 1) * 64;
  const int n_off = (w & 1) * 64;

  __shared__ unsigned short sm[16384];
  unsigned short* As = sm;
  unsigned short* Bs = sm + 8192;

  const int srow = lane >> 3;
  const int ssw  = ((lane & 7) ^ srow) * 8;
  const unsigned short* gA = wp + (size_t)(o0 + 32 * w + srow) * CC + ssw;
  const unsigned short* gB = aB + ((size_t)b * NN + n0 + 32 * w + srow) * CC + ssw;

  f32x4 acc[4][4] = {};

  for (int c0 = 0; c0 < CC; c0 += 64) {
    __syncthreads();
#pragma unroll
    for (int L = 0; L < 4; ++L) {
      gld_lds16(gA + (size_t)(8 * L) * CC + c0, &As[(32 * w + 8 * L) * 64]);
      gld_lds16(gB + (size_t)(8 * L) * CC + c0, &Bs[(32 * w + 8 * L) * 64]);
    }
    __syncthreads();
#pragma unroll
    for (int ks = 0; ks < 2; ++ks) {
      const int ph = ((ks * 4 + quad) ^ (l16 & 7)) * 8;
      bf16x8 af[4], bfr[4];
#pragma unroll
      for (int i = 0; i < 4; ++i) {
        af[i]  = *(const bf16x8*)&As[(m_off + 16 * i + l16) * 64 + ph];
        bfr[i] = *(const bf16x8*)&Bs[(n_off + 16 * i + l16) * 64 + ph];
      }
#pragma unroll
      for (int i = 0; i < 4; ++i)
#pragma unroll
        for (int j = 0; j < 4; ++j)
          acc[i][j] = __builtin_amdgcn_mfma_f32_16x16x32_bf16(af[i], bfr[j], acc[i][j], 0, 0, 0);
    }
  }

#pragma unroll
  for (int i = 0; i < 4; ++i) {
#pragma unroll
    for (int r = 0; r < 4; ++r) {
      const int o = o0 + m_off + 16 * i + quad * 4 + r;
      const float bv = bias[o];
      float* orow = out + ((size_t)b * CC + o) * NN + n0 + n_off;
#pragma unroll
      for (int j = 0; j < 4; ++j)
        orow[16 * j + l16] = acc[i][j][r] + bv;
    }
  }
}

// ---------------------------------------------------------------------------
extern "C" void kernel_launch(void* const* d_in, const int* in_sizes, int n_in,
                              void* d_out, int out_size, void* d_ws, size_t ws_size,
                              hipStream_t stream) {
  const float* x      = (const float*)d_in[0];
  const float* w_qkv  = (const float*)d_in[1];
  const float* w_proj = (const float*)d_in[2];
  const float* b_proj = (const float*)d_in[3];
  char* wsb  = (char*)d_ws;
  float* out = (float*)d_out;

  unsigned short* xT  = (unsigned short*)(wsb + XT_OFF);
  unsigned short* wq  = (unsigned short*)(wsb + WQ_OFF);
  unsigned short* wp  = (unsigned short*)(wsb + WP_OFF);
  unsigned short* qb  = (unsigned short*)(wsb + QB_OFF);
  unsigned short* kb_ = (unsigned short*)(wsb + KB_OFF);
  unsigned short* vt  = (unsigned short*)(wsb + VT_OFF);
  unsigned short* aB  = (unsigned short*)(wsb + AB_OFF);

  prep_w<<<512, 256, 0, stream>>>(w_qkv, w_proj, wq, wp);
  prep_xT<<<dim3(16, 8, BB), 256, 0, stream>>>(x, xT);
  qkv_mfma<<<dim3(8, 12, BB), 256, 0, stream>>>(wq, xT, qb, kb_, vt);
  attn_mfma<<<dim3(BB * NH, NN / 128), 256, 0, stream>>>(qb, kb_, vt, aB);
  proj_mfma<<<dim3(8, 4, BB), 256, 0, stream>>>(wp, aB, b_proj, out);
}

// Round 3
// 191.186 us; speedup vs baseline: 1.0531x; 1.0179x over previous
//
#include <hip/hip_runtime.h>
#include <hip/hip_bf16.h>
#include <math.h>

#define BB 16
#define CC 512
#define NH 8
#define HD 64
#define NN 1024   // H*W
#define THREEC 1536

// Q pre-scale: (1/sqrt(64)) * log2(e)  -> softmax via raw v_exp_f32 (2^x)
#define QSCALE 0.18033688f

typedef __attribute__((ext_vector_type(8))) short bf16x8;
typedef __attribute__((ext_vector_type(4))) float f32x4;
typedef __attribute__((ext_vector_type(16))) float f32x16;

#if __has_builtin(__builtin_amdgcn_exp2f)
#define EXP2F __builtin_amdgcn_exp2f
#else
#define EXP2F exp2f
#endif

// workspace byte offsets
#define XT_OFF 0u           // bf16 x^T [b][n][c]          (16.78 MB)
#define WQ_OFF 16777216u    // bf16 w_qkv [1536][512]      (1.57 MB)
#define WP_OFF 18350080u    // bf16 w_proj [512][512]      (0.52 MB)
#define QB_OFF 18874368u    // bf16 Q (scaled QSCALE) [bh][n][d]
#define KB_OFF 35651584u    // bf16 K [bh][n][d]
#define VT_OFF 52428800u    // bf16 V^T [bh][d][n]
#define AB_OFF 69206016u    // bf16 attn-out [b][n][c]
// end 85983232 (82 MiB)

static __device__ inline unsigned short f2bf(float f) {
  union { float f; unsigned u; } v; v.f = f;
  unsigned r = v.u + 0x7fffu + ((v.u >> 16) & 1u);
  return (unsigned short)(r >> 16);
}

// pack two f32 -> two bf16 in a u32 (lo = a, hi = b)
static __device__ inline unsigned pk2bf(float a, float b) {
#if defined(__AMDGCN__) && __has_builtin(__builtin_amdgcn_cvt_pk_bf16_f32)
  typedef __attribute__((ext_vector_type(2))) __bf16 bfp2;
  union { bfp2 v; unsigned u; } z;
  z.v = __builtin_amdgcn_cvt_pk_bf16_f32(a, b);
  return z.u;
#else
  return (unsigned)f2bf(a) | ((unsigned)f2bf(b) << 16);
#endif
}

static __device__ inline void gld_lds16(const unsigned short* g, unsigned short* l) {
  __builtin_amdgcn_global_load_lds(
      (const __attribute__((address_space(1))) unsigned int*)g,
      (__attribute__((address_space(3))) unsigned int*)l, 16, 0, 0);
}

// ---------------------------------------------------------------------------
// prep_w: convert w_qkv (786432) + w_proj (262144) fp32 -> bf16
// ---------------------------------------------------------------------------
__global__ __launch_bounds__(256) void prep_w(const float* __restrict__ wqkv,
                                              const float* __restrict__ wproj,
                                              unsigned short* __restrict__ dq,
                                              unsigned short* __restrict__ dp) {
  const size_t i8 = ((size_t)blockIdx.x * 256 + threadIdx.x) * 8;
  const float* src;
  unsigned short* dst;
  if (i8 < 786432u) { src = wqkv + i8; dst = dq + i8; }
  else              { src = wproj + (i8 - 786432u); dst = dp + (i8 - 786432u); }
  float4 a = *(const float4*)src;
  float4 b = *(const float4*)(src + 4);
  unsigned short pk[8] = {f2bf(a.x), f2bf(a.y), f2bf(a.z), f2bf(a.w),
                          f2bf(b.x), f2bf(b.y), f2bf(b.z), f2bf(b.w)};
  *(uint4*)dst = *(const uint4*)pk;
}

// ---------------------------------------------------------------------------
// prep_xT: x [b][c][n] fp32 -> xT [b][n][c] bf16. 64x64 LDS tile transpose.
// ---------------------------------------------------------------------------
__global__ __launch_bounds__(256) void prep_xT(const float* __restrict__ x,
                                               unsigned short* __restrict__ xT) {
  const int b  = blockIdx.z;
  const int c0 = blockIdx.y * 64;
  const int n0 = blockIdx.x * 64;
  __shared__ float tile[64][65];
  const int t  = threadIdx.x;
  const int cl = t >> 4, n4 = (t & 15) * 4;
#pragma unroll
  for (int r = 0; r < 4; ++r) {
    float4 v = *(const float4*)&x[((size_t)b * CC + c0 + cl + 16 * r) * NN + n0 + n4];
    *(float4*)&tile[cl + 16 * r][n4] = v;
  }
  __syncthreads();
  const int nl = t >> 4, c4 = (t & 15) * 4;
#pragma unroll
  for (int r = 0; r < 4; ++r) {
    ushort4 p;
    p.x = f2bf(tile[c4 + 0][nl + 16 * r]);
    p.y = f2bf(tile[c4 + 1][nl + 16 * r]);
    p.z = f2bf(tile[c4 + 2][nl + 16 * r]);
    p.w = f2bf(tile[c4 + 3][nl + 16 * r]);
    *(ushort4*)&xT[((size_t)b * NN + n0 + nl + 16 * r) * CC + c0 + c4] = p;
  }
}

// ---------------------------------------------------------------------------
// qkv_mfma: [1536x512] @ [512x1024] per batch, bf16 MFMA, 128x128 tile BK=64.
// ---------------------------------------------------------------------------
__global__ __launch_bounds__(256) void qkv_mfma(const unsigned short* __restrict__ wq,
                                                const unsigned short* __restrict__ xT,
                                                unsigned short* __restrict__ qb,
                                                unsigned short* __restrict__ kb_,
                                                unsigned short* __restrict__ vt) {
  const int b  = blockIdx.z;
  const int o0 = blockIdx.y * 128;
  const int n0 = blockIdx.x * 128;
  const int t  = threadIdx.x;
  const int w    = t >> 6;
  const int lane = t & 63;
  const int quad = lane >> 4;
  const int l16  = lane & 15;
  const int m_off = (w >> 1) * 64;
  const int n_off = (w & 1) * 64;

  __shared__ unsigned short sm[17408];
  unsigned short* As = sm;
  unsigned short* Bs = sm + 8192;

  const int which = o0 >> 9;       // 0=Q,1=K,2=V
  const bool vmode = (which == 2);

  const int srow = lane >> 3;
  const int ssw  = ((lane & 7) ^ srow) * 8;
  const unsigned short* gA = wq + (size_t)(o0 + 32 * w + srow) * CC + ssw;
  const unsigned short* gB = xT + ((size_t)b * NN + n0 + 32 * w + srow) * CC + ssw;

  f32x4 acc[4][4] = {};

  for (int c0 = 0; c0 < CC; c0 += 64) {
    __syncthreads();
#pragma unroll
    for (int L = 0; L < 4; ++L) {
      gld_lds16(gA + (size_t)(8 * L) * CC + c0, &As[(32 * w + 8 * L) * 64]);
      gld_lds16(gB + (size_t)(8 * L) * CC + c0, &Bs[(32 * w + 8 * L) * 64]);
    }
    __syncthreads();
    const unsigned short* Af = vmode ? Bs : As;
    const unsigned short* Bf = vmode ? As : Bs;
#pragma unroll
    for (int ks = 0; ks < 2; ++ks) {
      const int ph = ((ks * 4 + quad) ^ (l16 & 7)) * 8;
      bf16x8 af[4], bfr[4];
#pragma unroll
      for (int i = 0; i < 4; ++i) {
        af[i]  = *(const bf16x8*)&Af[(m_off + 16 * i + l16) * 64 + ph];
        bfr[i] = *(const bf16x8*)&Bf[(n_off + 16 * i + l16) * 64 + ph];
      }
#pragma unroll
      for (int i = 0; i < 4; ++i)
#pragma unroll
        for (int j = 0; j < 4; ++j)
          acc[i][j] = __builtin_amdgcn_mfma_f32_16x16x32_bf16(af[i], bfr[j], acc[i][j], 0, 0, 0);
    }
  }

  __syncthreads();
  const float sc = (which == 0) ? QSCALE : 1.0f;
#pragma unroll
  for (int i = 0; i < 4; ++i) {
#pragma unroll
    for (int j = 0; j < 4; ++j) {
      const int Drow = m_off + 16 * i + quad * 4;
      const int Dcol = n_off + 16 * j + l16;
      ushort4 p;
      p.x = f2bf(acc[i][j][0] * sc);
      p.y = f2bf(acc[i][j][1] * sc);
      p.z = f2bf(acc[i][j][2] * sc);
      p.w = f2bf(acc[i][j][3] * sc);
      *(ushort4*)&sm[Dcol * 136 + Drow] = p;
    }
  }
  __syncthreads();
  const int lrow = t >> 1;
  const int half = t & 1;
  const unsigned short* src = &sm[lrow * 136 + 64 * half];
  if (!vmode) {
    const int hh = ((o0 >> 6) & 7) + half;
    unsigned short* dst = (which == 0 ? qb : kb_) +
        ((size_t)(b * NH + hh) * NN + n0 + lrow) * HD;
#pragma unroll
    for (int i = 0; i < 8; ++i) *(uint4*)(dst + 8 * i) = *(const uint4*)(src + 8 * i);
  } else {
    const int hh = ((o0 + lrow) >> 6) & 7;
    const int d  = lrow & 63;
    unsigned short* dst = vt + ((size_t)(b * NH + hh) * HD + d) * NN + n0 + 64 * half;
#pragma unroll
    for (int i = 0; i < 8; ++i) *(uint4*)(dst + 8 * i) = *(const uint4*)(src + 8 * i);
  }
}

// ---------------------------------------------------------------------------
// attn_mfma v6: 32x32x16 MFMA, no-max softmax (exp2, Q pre-scaled by log2e/8).
// Key-permuted A-operand reads (rho = swap bits 2,3 of lane) make packed
// S^T C-regs directly usable as the PV B-fragment -> zero cross-lane swaps.
// v6: SKEWED SOFTWARE PIPELINE (T15). v5's l-on-MFMA reverted (net loss:
// the VALU adds were free, the extra MFMAs were not). LDS split into
// independent K-dbuf {kb0,kb1} and V-dbuf {vb0,vb1} (4 x 8KB = 32KB).
// Iteration i: stage K[i+1] + V[i]; compute QK(i) and PV(i-1). Every QK
// MFMA cluster is adjacent to an independent PV cluster + independent
// exp2/pack VALU work -> the per-chunk serial chain (QK -> exp2 -> pack
// -> PV) no longer bounds the loop. Buffer lifetimes: K[i+1] overwrites
// K[i-1] (last read iter i-1), V[i] overwrites V[i-2] (last read iter
// i-1); both fenced by the single per-iteration barrier. P carried packed
// across the barrier; PV consumes old P before SM overwrites it.
// ---------------------------------------------------------------------------
__global__ __launch_bounds__(256) void attn_mfma(const unsigned short* __restrict__ Qg,
                                                 const unsigned short* __restrict__ Kg,
                                                 const unsigned short* __restrict__ Vtg,
                                                 unsigned short* __restrict__ attnB) {
  const int bh = blockIdx.x;     // id % 8 == bh % 8 -> XCD affinity
  const int b  = bh >> 3;
  const int h  = bh & 7;
  const int n0 = blockIdx.y * 128;
  const int t  = threadIdx.x;
  const int w    = t >> 6;
  const int lane = t & 63;
  const int l31  = lane & 31;
  const int hi   = lane >> 5;

  // kb0 = sm[0,4096), kb1 = sm[4096,8192), vb0 = sm[8192,12288), vb1 = rest
  __shared__ unsigned short sm[16384];

  // Q B-fragments (whole kernel): B[n=query=l31][k=d=16c+8hi+j]
  const unsigned short* qrow = Qg + ((size_t)bh * NN + n0 + w * 32 + l31) * HD + hi * 8;
  bf16x8 qf[4];
#pragma unroll
  for (int c = 0; c < 4; ++c) qf[c] = *(const bf16x8*)(qrow + 16 * c);

  // K A-row permutation: rho(l) swaps bits 2 and 3
  const int krow = (l31 & ~12) | ((l31 & 4) << 1) | ((l31 & 8) >> 1);
  const int ksw  = krow & 7;
  const int vsw  = l31 & 7;

  const f32x16 fz = {};

  f32x16 oacc[2] = {};   // O^T: D[m=d][n=query]
  float lx = 0.f, ly = 0.f;

  // staging: wave w covers rows [16w,16w+16) of both K (keys) and V^T (d).
  const int srow = lane >> 3;                     // 0..7
  const int sgrp = (lane & 7) ^ (srow & 7);       // swizzled source col group
  const unsigned short* kstage = Kg + (size_t)bh * NN * HD +
                                 (size_t)(16 * w + srow) * HD + sgrp * 8;
  const unsigned short* vstage = Vtg + (size_t)bh * HD * NN +
                                 (size_t)(16 * w + srow) * NN + sgrp * 8;
  const int kso0 = (16 * w) * 64;
  const int kso1 = (16 * w + 8) * 64;

  auto stageK = [&](int j0, int p) {
    unsigned short* Kp = sm + p * 4096;
    gld_lds16(kstage + (size_t)j0 * HD, Kp + kso0);
    gld_lds16(kstage + (size_t)(j0 + 8) * HD, Kp + kso1);
  };
  auto stageV = [&](int j0, int p) {
    unsigned short* Vp = sm + 8192 + p * 4096;
    gld_lds16(vstage + j0, Vp + kso0);
    gld_lds16(vstage + (size_t)8 * NN + j0, Vp + kso1);
  };

  // QK for sub-block kb of the chunk in Ks: S^T = K_rho @ Q (contract d)
  auto QK = [&](const unsigned short* Ks, int kb) -> f32x16 {
    const unsigned short* krp = &Ks[(32 * kb + krow) * 64];
    bf16x8 kf0 = *(const bf16x8*)(krp + (((0 + hi) ^ ksw) * 8));
    f32x16 st = __builtin_amdgcn_mfma_f32_32x32x16_bf16(kf0, qf[0], fz, 0, 0, 0);
#pragma unroll
    for (int c = 1; c < 4; ++c) {
      bf16x8 kf = *(const bf16x8*)(krp + (((2 * c + hi) ^ ksw) * 8));
      st = __builtin_amdgcn_mfma_f32_32x32x16_bf16(kf, qf[c], st, 0, 0, 0);
    }
    return st;
  };
  // exp2 + l-accum + pack; P pairs ARE the PV B-fragment (rho absorbed)
  auto SM = [&](const f32x16& st, unsigned* P) {
#pragma unroll
    for (int i = 0; i < 8; ++i) {
      float ea = EXP2F(st[2 * i]);
      float eb = EXP2F(st[2 * i + 1]);
      lx += ea; ly += eb;
      P[i] = pk2bf(ea, eb);
    }
  };
  auto PV = [&](const unsigned* P, const unsigned short* Vp, int kb) {
#pragma unroll
    for (int g = 0; g < 2; ++g) {
      union { unsigned u[4]; bf16x8 v; } cv;
      cv.u[0] = P[4 * g + 0]; cv.u[1] = P[4 * g + 1];
      cv.u[2] = P[4 * g + 2]; cv.u[3] = P[4 * g + 3];
#pragma unroll
      for (int mt = 0; mt < 2; ++mt) {
        const int vrow = 32 * mt + l31;
        bf16x8 vf = *(const bf16x8*)&Vp[vrow * 64 + (((4 * kb + 2 * g + hi) ^ vsw) * 8)];
        oacc[mt] = __builtin_amdgcn_mfma_f32_32x32x16_bf16(vf, cv.v, oacc[mt], 0, 0, 0);
      }
    }
  };

  unsigned P0[8], P1[8];

  // prologue: K[0]
  stageK(0, 0);
  // iteration 0: QK(0) only
  __syncthreads();
  stageK(64, 1);
  stageV(0, 0);
  {
    f32x16 st = QK(sm, 0);
    SM(st, P0);
    st = QK(sm, 1);
    SM(st, P1);
  }

#pragma unroll 1
  for (int i = 1; i < 16; ++i) {
    // barrier publishes K[i] and V[i-1]; fences reuse of K[i-1]/V[i-2] bufs
    __syncthreads();
    if (i < 15) stageK(64 * (i + 1), (i + 1) & 1);
    stageV(64 * i, i & 1);
    const unsigned short* Ks = sm + (i & 1) * 4096;
    const unsigned short* Vp = sm + 8192 + ((i - 1) & 1) * 4096;

    __builtin_amdgcn_s_setprio(1);
    f32x16 st = QK(Ks, 0);      // chunk i, sub-block 0
    PV(P0, Vp, 0);              // chunk i-1, sub-block 0 (independent)
    __builtin_amdgcn_s_setprio(0);
    SM(st, P0);                 // overwrites P0 after PV consumed it

    __builtin_amdgcn_s_setprio(1);
    st = QK(Ks, 1);
    PV(P1, Vp, 1);
    __builtin_amdgcn_s_setprio(0);
    SM(st, P1);
  }

  // drain: PV of chunk 15 (V[15] published by this barrier)
  __syncthreads();
  {
    const unsigned short* Vp = sm + 8192 + 4096;   // vb1 = V[15]
    __builtin_amdgcn_s_setprio(1);
    PV(P0, Vp, 0);
    PV(P1, Vp, 1);
    __builtin_amdgcn_s_setprio(0);
  }

  float lsum = lx + ly;
  lsum += __shfl_xor(lsum, 32);
  const float inv = 1.0f / lsum;

  // epilogue: wave-private LDS [query][d] (pitch 72) in sm[0,9216) —
  // disjoint from vb1; all waves past the drain barrier, kb/vb0 dead.
  unsigned short* Es = sm + w * 2304;   // 32 * 72 shorts per wave
#pragma unroll
  for (int mt = 0; mt < 2; ++mt) {
#pragma unroll
    for (int rr = 0; rr < 4; ++rr) {
      const int d = 32 * mt + 8 * rr + 4 * hi;
      ushort4 p;
      p.x = f2bf(oacc[mt][4 * rr + 0] * inv);
      p.y = f2bf(oacc[mt][4 * rr + 1] * inv);
      p.z = f2bf(oacc[mt][4 * rr + 2] * inv);
      p.w = f2bf(oacc[mt][4 * rr + 3] * inv);
      *(ushort4*)&Es[l31 * 72 + d] = p;
    }
  }
  const int q    = lane >> 1;
  const int half = lane & 1;
  const unsigned short* src = &Es[q * 72 + 32 * half];
  unsigned short* gdst = attnB + ((size_t)b * NN + n0 + w * 32 + q) * CC + h * HD + 32 * half;
#pragma unroll
  for (int i = 0; i < 4; ++i) *(uint4*)(gdst + 8 * i) = *(const uint4*)(src + 8 * i);
}

// ---------------------------------------------------------------------------
// proj_mfma: out = w_proj @ attn + bias, bf16 MFMA, fp32 out [b][c][n].
// ---------------------------------------------------------------------------
__global__ __launch_bounds__(256) void proj_mfma(const unsigned short* __restrict__ wp,
                                                 const unsigned short* __restrict__ aB,
                                                 const float* __restrict__ bias,
                                                 float* __restrict__ out) {
  const int b  = blockIdx.z;
  const int o0 = blockIdx.y * 128;
  const int n0 = blockIdx.x * 128;
  const int t  = threadIdx.x;
  const int w    = t >> 6;
  const int lane = t & 63;
  const int quad = lane >> 4;
  const int l16  = lane & 15;
  const int m_off = (w >> 1) * 64;
  const int n_off = (w & 1) * 64;

  __shared__ unsigned short sm[16384];
  unsigned short* As = sm;
  unsigned short* Bs = sm + 8192;

  const int srow = lane >> 3;
  const int ssw  = ((lane & 7) ^ srow) * 8;
  const unsigned short* gA = wp + (size_t)(o0 + 32 * w + srow) * CC + ssw;
  const unsigned short* gB = aB + ((size_t)b * NN + n0 + 32 * w + srow) * CC + ssw;

  f32x4 acc[4][4] = {};

  for (int c0 = 0; c0 < CC; c0 += 64) {
    __syncthreads();
#pragma unroll
    for (int L = 0; L < 4; ++L) {
      gld_lds16(gA + (size_t)(8 * L) * CC + c0, &As[(32 * w + 8 * L) * 64]);
      gld_lds16(gB + (size_t)(8 * L) * CC + c0, &Bs[(32 * w + 8 * L) * 64]);
    }
    __syncthreads();
#pragma unroll
    for (int ks = 0; ks < 2; ++ks) {
      const int ph = ((ks * 4 + quad) ^ (l16 & 7)) * 8;
      bf16x8 af[4], bfr[4];
#pragma unroll
      for (int i = 0; i < 4; ++i) {
        af[i]  = *(const bf16x8*)&As[(m_off + 16 * i + l16) * 64 + ph];
        bfr[i] = *(const bf16x8*)&Bs[(n_off + 16 * i + l16) * 64 + ph];
      }
#pragma unroll
      for (int i = 0; i < 4; ++i)
#pragma unroll
        for (int j = 0; j < 4; ++j)
          acc[i][j] = __builtin_amdgcn_mfma_f32_16x16x32_bf16(af[i], bfr[j], acc[i][j], 0, 0, 0);
    }
  }

#pragma unroll
  for (int i = 0; i < 4; ++i) {
#pragma unroll
    for (int r = 0; r < 4; ++r) {
      const int o = o0 + m_off + 16 * i + quad * 4 + r;
      const float bv = bias[o];
      float* orow = out + ((size_t)b * CC + o) * NN + n0 + n_off;
#pragma unroll
      for (int j = 0; j < 4; ++j)
        orow[16 * j + l16] = acc[i][j][r] + bv;
    }
  }
}

// ---------------------------------------------------------------------------
extern "C" void kernel_launch(void* const* d_in, const int* in_sizes, int n_in,
                              void* d_out, int out_size, void* d_ws, size_t ws_size,
                              hipStream_t stream) {
  const float* x      = (const float*)d_in[0];
  const float* w_qkv  = (const float*)d_in[1];
  const float* w_proj = (const float*)d_in[2];
  const float* b_proj = (const float*)d_in[3];
  char* wsb  = (char*)d_ws;
  float* out = (float*)d_out;

  unsigned short* xT  = (unsigned short*)(wsb + XT_OFF);
  unsigned short* wq  = (unsigned short*)(wsb + WQ_OFF);
  unsigned short* wp  = (unsigned short*)(wsb + WP_OFF);
  unsigned short* qb  = (unsigned short*)(wsb + QB_OFF);
  unsigned short* kb_ = (unsigned short*)(wsb + KB_OFF);
  unsigned short* vt  = (unsigned short*)(wsb + VT_OFF);
  unsigned short* aB  = (unsigned short*)(wsb + AB_OFF);

  prep_w<<<512, 256, 0, stream>>>(w_qkv, w_proj, wq, wp);
  prep_xT<<<dim3(16, 8, BB), 256, 0, stream>>>(x, xT);
  qkv_mfma<<<dim3(8, 12, BB), 256, 0, stream>>>(wq, xT, qb, kb_, vt);
  attn_mfma<<<dim3(BB * NH, NN / 128), 256, 0, stream>>>(qb, kb_, vt, aB);
  proj_mfma<<<dim3(8, 4, BB), 256, 0, stream>>>(wp, aB, b_proj, out);
}